// Round 12
// baseline (293.732 us; speedup 1.0000x reference)
//
#include <hip/hip_runtime.h>
#include <hip/hip_bf16.h>
#include <hip/hip_fp16.h>
#include <math.h>

#define NEG_SLOPE 0.2f
#define GAT_EPS 1e-16f
#define NBMAX 512          // buckets of 256 dsts: N <= 131072 (src fits 17 bits)
#define CAP   6144         // fixed per-bucket capacity (mean 4352, +28 sigma)

// ---------------- K_A: fused [part blocks | gemm blocks], 1024 thr -----------
// part path (blocks [0,G2)): bucket edges, register-prefetched.
// gemm path: h1 = X @ W1 (fp16, HEAD-MAJOR [h][n][16]) + scores [h][n].
__global__ __launch_bounds__(1024) void k_partA(
    const int* __restrict__ ei, int E, int N, int NB, int G2,
    int* __restrict__ cnt, unsigned int* __restrict__ bp,
    const float* __restrict__ x, const float* __restrict__ W1,
    const float* __restrict__ a_src, const float* __restrict__ a_dst,
    __half* __restrict__ h1h, float* __restrict__ s_src_h, float* __restrict__ s_dst_h)
{
    __shared__ int hist[NBMAX];
    __shared__ int base[NBMAX];
    int t = threadIdx.x;
    if (blockIdx.x >= G2) {
        // ---- gemm1 path: thread -> (node n, channel group j4 of 4) ----
        int gid = (blockIdx.x - G2) * 1024 + t;
        int n = gid >> 5;
        int j4 = gid & 31;
        if (n >= N) return;
        const float4* xr = (const float4*)(x + (size_t)n * 16);
        float4 x0 = xr[0], x1 = xr[1], x2 = xr[2], x3 = xr[3];
        float xs[16] = { x0.x,x0.y,x0.z,x0.w, x1.x,x1.y,x1.z,x1.w,
                         x2.x,x2.y,x2.z,x2.w, x3.x,x3.y,x3.z,x3.w };
        const float4* W4 = (const float4*)W1;   // [16][32] as float4
        float4 acc = {0.f, 0.f, 0.f, 0.f};
#pragma unroll
        for (int k = 0; k < 16; ++k) {
            float4 w = W4[k * 32 + j4];
            acc.x += xs[k] * w.x;
            acc.y += xs[k] * w.y;
            acc.z += xs[k] * w.z;
            acc.w += xs[k] * w.w;
        }
        int h = j4 >> 2, c4 = j4 & 3;
        union { __half2 h2v[2]; uint2 u; } pk;
        pk.h2v[0] = __floats2half2_rn(acc.x, acc.y);
        pk.h2v[1] = __floats2half2_rn(acc.z, acc.w);
        ((uint2*)h1h)[((size_t)h * N + n) * 4 + c4] = pk.u;
        float4 av = ((const float4*)a_src)[j4];
        float4 dv = ((const float4*)a_dst)[j4];
        float ps = acc.x*av.x + acc.y*av.y + acc.z*av.z + acc.w*av.w;
        float pd = acc.x*dv.x + acc.y*dv.y + acc.z*dv.z + acc.w*dv.w;
        ps += __shfl_xor(ps, 1); ps += __shfl_xor(ps, 2);
        pd += __shfl_xor(pd, 1); pd += __shfl_xor(pd, 2);
        if (c4 == 0) {
            s_src_h[(size_t)h * N + n] = ps;
            s_dst_h[(size_t)h * N + n] = pd;
        }
        return;
    }
    // ---- part path: prefetch 4 edges into regs, then hist/reserve/scatter ---
    int e0 = blockIdx.x * 4096;
    int srcs[4], dsts[4];
#pragma unroll
    for (int k = 0; k < 4; ++k) {
        int e = e0 + k * 1024 + t;
        if (e < E + N) {
            if (e < E) { srcs[k] = ei[e]; dsts[k] = ei[E + e]; }
            else       { srcs[k] = dsts[k] = e - E; }
        } else dsts[k] = -1;
    }
    if (t < NB) hist[t] = 0;
    __syncthreads();
#pragma unroll
    for (int k = 0; k < 4; ++k)
        if (dsts[k] >= 0) atomicAdd(&hist[dsts[k] >> 8], 1);
    __syncthreads();
    if (t < NB) {
        int c = hist[t];
        base[t] = (c > 0) ? atomicAdd(&cnt[t], c) : 0;
        hist[t] = 0;
    }
    __syncthreads();
#pragma unroll
    for (int k = 0; k < 4; ++k) {
        if (dsts[k] >= 0) {
            int b = dsts[k] >> 8;
            int r = base[b] + atomicAdd(&hist[b], 1);
            if (r < CAP)   // safety clamp (28-sigma headroom, never expected)
                bp[(size_t)b * CAP + r] =
                    ((unsigned)(dsts[k] & 255) << 17) | (unsigned)srcs[k];
        }
    }
}

// ---------------- K_B: per-bucket CSR build (512 thr, block-local) -----------
__global__ __launch_bounds__(512) void k_csr(
    const unsigned int* __restrict__ bp, const int* __restrict__ cnt,
    int* __restrict__ offs, int* __restrict__ ends,
    int* __restrict__ csr, int N)
{
    __shared__ int dcount[256];
    __shared__ int dtmp[256];
    __shared__ int doff[256];
    int b = blockIdx.x;
    int t = threadIdx.x;
    int rb = b * CAP;
    int m = cnt[b]; if (m > CAP) m = CAP;
    if (t < 256) dcount[t] = 0;
    __syncthreads();
    for (int i = t; i < m; i += 512) {
        atomicAdd(&dcount[bp[rb + i] >> 17], 1);
    }
    __syncthreads();
    int v = 0;
    if (t < 256) { v = dcount[t]; dtmp[t] = v; }
    __syncthreads();
    for (int off = 1; off < 256; off <<= 1) {
        int add = (t < 256 && t >= off) ? dtmp[t - off] : 0;
        __syncthreads();
        if (t < 256) dtmp[t] += add;
        __syncthreads();
    }
    if (t < 256) {
        doff[t] = dtmp[t] - v;      // exclusive within bucket
        int n = b * 256 + t;
        if (n < N) { offs[n] = rb + doff[t]; ends[n] = rb + dtmp[t]; }
        dcount[t] = 0;
    }
    __syncthreads();
    for (int i = t; i < m; i += 512) {
        unsigned int p = bp[rb + i];
        int dl = p >> 17;
        int r = atomicAdd(&dcount[dl], 1);
        csr[rb + doff[dl] + r] = (int)(p & 0x1FFFFu);
    }
}

// ---------------- K5: HEAD-SHARDED layer-1 aggregate + partial W2 dot --------
// block bi -> (head h = bi&7, dst chunk = bi>>3). Round-robin dispatch puts
// head h on XCD h -> per-XCD hot set = 3.2MB h1 slice (L2-resident).
// 2 threads per dst (even/odd edges, 2-edge unroll each).
__global__ __launch_bounds__(256) void k_agg1h(
    const __half* __restrict__ h1h, const float* __restrict__ s_src_h,
    const float* __restrict__ s_dst_h, const float* __restrict__ b1,
    const float* __restrict__ W2,
    const int* __restrict__ offs, const int* __restrict__ ends,
    const int* __restrict__ csr_src,
    float4* __restrict__ h2part, int N)
{
    int h = blockIdx.x & 7;
    int chunk = blockIdx.x >> 3;
    int t = threadIdx.x;
    int n = chunk * 128 + (t >> 1);
    int half = t & 1;
    if (n >= N) return;
    int beg = offs[n], end = ends[n];
    const float* ssrc = s_src_h + (size_t)h * N;
    const __half* hbase = h1h + (size_t)h * N * 16;
    float sd = s_dst_h[(size_t)h * N + n];

    float z = 0.f;
    float acc[16];
#pragma unroll
    for (int c = 0; c < 16; ++c) acc[c] = 0.f;

    union U { float4 f; __half2 hh[4]; };
    int i = beg + half;
    for (; i + 2 < end; i += 4) {
        int sA = csr_src[i];
        int sB = csr_src[i + 2];
        const float4* hA = (const float4*)(hbase + (size_t)sA * 16);
        const float4* hB = (const float4*)(hbase + (size_t)sB * 16);
        U a0, a1, b0, b1v;
        a0.f = hA[0]; a1.f = hA[1];
        b0.f = hB[0]; b1v.f = hB[1];
        float eA = ssrc[sA] + sd;
        float eB = ssrc[sB] + sd;
        eA = (eA > 0.f) ? eA : NEG_SLOPE * eA;
        eB = (eB > 0.f) ? eB : NEG_SLOPE * eB;
        float pA = __expf(eA);
        float pB = __expf(eB);
        z += pA + pB;
#pragma unroll
        for (int k = 0; k < 4; ++k) {
            float2 vA = __half22float2(a0.hh[k]);
            float2 vB = __half22float2(b0.hh[k]);
            acc[2 * k]     += pA * vA.x + pB * vB.x;
            acc[2 * k + 1] += pA * vA.y + pB * vB.y;
        }
#pragma unroll
        for (int k = 0; k < 4; ++k) {
            float2 vA = __half22float2(a1.hh[k]);
            float2 vB = __half22float2(b1v.hh[k]);
            acc[8 + 2 * k] += pA * vA.x + pB * vB.x;
            acc[9 + 2 * k] += pA * vA.y + pB * vB.y;
        }
    }
    if (i < end) {
        int sA = csr_src[i];
        const float4* hA = (const float4*)(hbase + (size_t)sA * 16);
        U a0, a1;
        a0.f = hA[0]; a1.f = hA[1];
        float eA = ssrc[sA] + sd;
        eA = (eA > 0.f) ? eA : NEG_SLOPE * eA;
        float pA = __expf(eA);
        z += pA;
#pragma unroll
        for (int k = 0; k < 4; ++k) {
            float2 vA = __half22float2(a0.hh[k]);
            acc[2 * k]     += pA * vA.x;
            acc[2 * k + 1] += pA * vA.y;
        }
#pragma unroll
        for (int k = 0; k < 4; ++k) {
            float2 vA = __half22float2(a1.hh[k]);
            acc[8 + 2 * k] += pA * vA.x;
            acc[9 + 2 * k] += pA * vA.y;
        }
    }

    // merge the two halves (adjacent lanes)
    z += __shfl_xor(z, 1);
#pragma unroll
    for (int c = 0; c < 16; ++c) acc[c] += __shfl_xor(acc[c], 1);

    if (half == 0) {
        float inv = 1.f / (z + GAT_EPS);
        float r0 = 0.f, r1 = 0.f, r2 = 0.f;
        const float* bb = b1 + h * 16;
        const float* w2 = W2 + h * 16 * 3;
#pragma unroll
        for (int c = 0; c < 16; ++c) {
            float xc = fmaxf(acc[c] * inv + bb[c], 0.f);
            r0 += xc * w2[c * 3 + 0];
            r1 += xc * w2[c * 3 + 1];
            r2 += xc * w2[c * 3 + 2];
        }
        float4 pk = { r0, r1, r2, 0.f };
        h2part[(size_t)h * N + n] = pk;
    }
}

// ---------------- K5b: sum per-head partials -> h2 packed + scores -----------
__global__ __launch_bounds__(256) void k_score2(
    const float4* __restrict__ h2part, const float* __restrict__ a_src2,
    const float* __restrict__ a_dst2,
    float4* __restrict__ h2pk, float* __restrict__ s2d, int N)
{
    int n = blockIdx.x * 256 + threadIdx.x;
    if (n >= N) return;
    float r0 = 0.f, r1 = 0.f, r2 = 0.f;
#pragma unroll
    for (int h = 0; h < 8; ++h) {
        float4 v = h2part[(size_t)h * N + n];
        r0 += v.x; r1 += v.y; r2 += v.z;
    }
    float ss = r0 * a_src2[0] + r1 * a_src2[1] + r2 * a_src2[2];
    float dd = r0 * a_dst2[0] + r1 * a_dst2[1] + r2 * a_dst2[2];
    float4 pk = { r0, r1, r2, ss };
    h2pk[n] = pk;
    s2d[n] = dd;
}

// ---------------- K6: layer-2 aggregate -> out. 8 threads per dst ------------
__global__ __launch_bounds__(256) void k_agg2(
    const float4* __restrict__ h2packed, const float* __restrict__ s2d,
    const float* __restrict__ b2,
    const int* __restrict__ offs, const int* __restrict__ ends,
    const int* __restrict__ csr_src,
    float* __restrict__ out, int N)
{
    int gid = blockIdx.x * 256 + threadIdx.x;
    if (gid >= N * 8) return;
    int n = gid >> 3;
    int t = gid & 7;
    int beg = offs[n], end = ends[n];
    float sd = s2d[n];
    float z = 0.f, a0 = 0.f, a1 = 0.f, a2 = 0.f;
    for (int i = beg + t; i < end; i += 8) {
        int src = csr_src[i];
        float4 v = h2packed[src];
        float s = v.w + sd;
        s = (s > 0.f) ? s : NEG_SLOPE * s;
        float p = __expf(s);
        z += p;
        a0 += p * v.x; a1 += p * v.y; a2 += p * v.z;
    }
#pragma unroll
    for (int m = 4; m >= 1; m >>= 1) {
        z  += __shfl_xor(z, m);
        a0 += __shfl_xor(a0, m);
        a1 += __shfl_xor(a1, m);
        a2 += __shfl_xor(a2, m);
    }
    if (t == 0) {
        float inv = 1.f / (z + GAT_EPS);
        out[(size_t)n * 3 + 0] = a0 * inv + b2[0];
        out[(size_t)n * 3 + 1] = a1 * inv + b2[1];
        out[(size_t)n * 3 + 2] = a2 * inv + b2[2];
    }
}

extern "C" void kernel_launch(void* const* d_in, const int* in_sizes, int n_in,
                              void* d_out, int out_size, void* d_ws, size_t ws_size,
                              hipStream_t stream)
{
    const float* feature = (const float*)d_in[0];
    const int*   ei      = (const int*)d_in[1];
    // d_in[2] edge_type: unused by reference
    const float* W1      = (const float*)d_in[3];
    const float* a_src1  = (const float*)d_in[4];
    const float* a_dst1  = (const float*)d_in[5];
    const float* b1      = (const float*)d_in[6];
    const float* W2      = (const float*)d_in[7];
    const float* a_src2  = (const float*)d_in[8];
    const float* a_dst2  = (const float*)d_in[9];
    const float* b2      = (const float*)d_in[10];

    const int N = in_sizes[0] / 16;
    const int E = in_sizes[1] / 2;
    const int ET = E + N;
    const int NB = (N + 255) >> 8;          // 391 for N=100000 (<= NBMAX)

    char* p = (char*)d_ws;
    auto alloc = [&](size_t bytes) -> void* {
        void* r = (void*)p;
        p += (bytes + 255) & ~(size_t)255;
        return r;
    };
    __half* h1h  = (__half*)alloc((size_t)N * 128 * 2);      // [8][N][16]
    float*  s1s  = (float*)alloc((size_t)N * 8 * 4);         // [8][N]
    float*  s1d  = (float*)alloc((size_t)N * 8 * 4);         // [8][N]
    float4* h2pt = (float4*)alloc((size_t)N * 8 * 16);       // [8][N] partials
    float4* h2pk = (float4*)alloc((size_t)N * 16);
    float*  s2dv = (float*)alloc((size_t)N * 4);
    int*    offs = (int*)alloc((size_t)N * 4);
    int*    ends = (int*)alloc((size_t)N * 4);
    int*    csr  = (int*)alloc((size_t)NB * CAP * 4);
    unsigned int* bp = (unsigned int*)alloc((size_t)NB * CAP * 4);
    int*    cnt  = (int*)alloc((size_t)NBMAX * 4);

    hipMemsetAsync(cnt, 0, (size_t)NB * 4, stream);

    // fused: edge partition (G2 blocks, first) + layer-1 node transform
    int G2 = (ET + 4095) / 4096;
    int G1 = (N * 32 + 1023) / 1024;
    k_partA<<<G2 + G1, 1024, 0, stream>>>(
        ei, E, N, NB, G2, cnt, bp,
        feature, W1, a_src1, a_dst1, h1h, s1s, s1d);

    // per-bucket CSR build
    k_csr<<<NB, 512, 0, stream>>>(bp, cnt, offs, ends, csr, N);

    // head-sharded layer-1 aggregation (+ partial W2 dot)
    int chunks = (N + 127) / 128;
    k_agg1h<<<chunks * 8, 256, 0, stream>>>(
        h1h, s1s, s1d, b1, W2, offs, ends, csr, h2pt, N);

    // sum partials -> h2 + scores
    k_score2<<<(N + 255) / 256, 256, 0, stream>>>(
        h2pt, a_src2, a_dst2, h2pk, s2dv, N);

    // layer-2 aggregation -> out
    k_agg2<<<(N * 8 + 255) / 256, 256, 0, stream>>>(
        h2pk, s2dv, b2, offs, ends, csr, (float*)d_out, N);
}

// Round 13
// 176.908 us; speedup vs baseline: 1.6604x; 1.6604x over previous
//
#include <hip/hip_runtime.h>
#include <hip/hip_bf16.h>
#include <hip/hip_fp16.h>
#include <math.h>

#define NEG_SLOPE 0.2f
#define GAT_EPS 1e-16f
#define NBMAX 512          // buckets of 256 dsts: N <= 131072 (src fits 17 bits)
#define CAP   6144         // fixed per-bucket capacity (mean 4352, +28 sigma)

// ---------------- K1: h1 = X @ W1 (fp16) + per-head scores; 4 ch/thread ------
__global__ __launch_bounds__(256) void k_gemm1(
    const float* __restrict__ x, const float* __restrict__ W1,
    const float* __restrict__ a_src, const float* __restrict__ a_dst,
    __half* __restrict__ h1, float* __restrict__ s_src, float* __restrict__ s_dst,
    int N)
{
    int gid = blockIdx.x * 256 + threadIdx.x;
    int n = gid >> 5;
    int j4 = gid & 31;
    if (n >= N) return;
    const float4* xr = (const float4*)(x + (size_t)n * 16);
    float4 x0 = xr[0], x1 = xr[1], x2 = xr[2], x3 = xr[3];
    float xs[16] = { x0.x,x0.y,x0.z,x0.w, x1.x,x1.y,x1.z,x1.w,
                     x2.x,x2.y,x2.z,x2.w, x3.x,x3.y,x3.z,x3.w };
    const float4* W4 = (const float4*)W1;   // [16][32] as float4
    float4 acc = {0.f, 0.f, 0.f, 0.f};
#pragma unroll
    for (int k = 0; k < 16; ++k) {
        float4 w = W4[k * 32 + j4];
        acc.x += xs[k] * w.x;
        acc.y += xs[k] * w.y;
        acc.z += xs[k] * w.z;
        acc.w += xs[k] * w.w;
    }
    union { __half2 h2v[2]; uint2 u; } pk;
    pk.h2v[0] = __floats2half2_rn(acc.x, acc.y);
    pk.h2v[1] = __floats2half2_rn(acc.z, acc.w);
    ((uint2*)h1)[(size_t)n * 32 + j4] = pk.u;
    float4 av = ((const float4*)a_src)[j4];
    float4 dv = ((const float4*)a_dst)[j4];
    float ps = acc.x*av.x + acc.y*av.y + acc.z*av.z + acc.w*av.w;
    float pd = acc.x*dv.x + acc.y*dv.y + acc.z*dv.z + acc.w*dv.w;
    ps += __shfl_xor(ps, 1); ps += __shfl_xor(ps, 2);
    pd += __shfl_xor(pd, 1); pd += __shfl_xor(pd, 2);
    if ((j4 & 3) == 0) {
        int h = j4 >> 2;
        s_src[n * 8 + h] = ps;
        s_dst[n * 8 + h] = pd;
    }
}

// ---------------- K2: partition edges into buckets (1024 thr, reg-prefetch) --
__global__ __launch_bounds__(1024) void k_part(
    const int* __restrict__ ei, int E, int N, int NB,
    int* __restrict__ cnt, unsigned int* __restrict__ bp)
{
    __shared__ int hist[NBMAX];
    __shared__ int base[NBMAX];
    int t = threadIdx.x;
    int e0 = blockIdx.x * 4096;
    int srcs[4], dsts[4];
#pragma unroll
    for (int k = 0; k < 4; ++k) {
        int e = e0 + k * 1024 + t;
        if (e < E + N) {
            if (e < E) { srcs[k] = ei[e]; dsts[k] = ei[E + e]; }
            else       { srcs[k] = dsts[k] = e - E; }
        } else dsts[k] = -1;
    }
    if (t < NB) hist[t] = 0;
    __syncthreads();
#pragma unroll
    for (int k = 0; k < 4; ++k)
        if (dsts[k] >= 0) atomicAdd(&hist[dsts[k] >> 8], 1);
    __syncthreads();
    if (t < NB) {
        int c = hist[t];
        base[t] = (c > 0) ? atomicAdd(&cnt[t], c) : 0;
        hist[t] = 0;
    }
    __syncthreads();
#pragma unroll
    for (int k = 0; k < 4; ++k) {
        if (dsts[k] >= 0) {
            int b = dsts[k] >> 8;
            int r = base[b] + atomicAdd(&hist[b], 1);
            if (r < CAP)   // safety clamp (28-sigma headroom, never expected)
                bp[(size_t)b * CAP + r] =
                    ((unsigned)(dsts[k] & 255) << 17) | (unsigned)srcs[k];
        }
    }
}

// ---------------- K_B: per-bucket CSR build (512 thr, block-local) -----------
__global__ __launch_bounds__(512) void k_csr(
    const unsigned int* __restrict__ bp, const int* __restrict__ cnt,
    int* __restrict__ offs, int* __restrict__ ends,
    int* __restrict__ csr, int N)
{
    __shared__ int dcount[256];
    __shared__ int dtmp[256];
    __shared__ int doff[256];
    int b = blockIdx.x;
    int t = threadIdx.x;
    int rb = b * CAP;
    int m = cnt[b]; if (m > CAP) m = CAP;
    if (t < 256) dcount[t] = 0;
    __syncthreads();
    for (int i = t; i < m; i += 512) {
        atomicAdd(&dcount[bp[rb + i] >> 17], 1);
    }
    __syncthreads();
    int v = 0;
    if (t < 256) { v = dcount[t]; dtmp[t] = v; }
    __syncthreads();
    for (int off = 1; off < 256; off <<= 1) {
        int add = (t < 256 && t >= off) ? dtmp[t - off] : 0;
        __syncthreads();
        if (t < 256) dtmp[t] += add;
        __syncthreads();
    }
    if (t < 256) {
        doff[t] = dtmp[t] - v;      // exclusive within bucket
        int n = b * 256 + t;
        if (n < N) { offs[n] = rb + doff[t]; ends[n] = rb + dtmp[t]; }
        dcount[t] = 0;
    }
    __syncthreads();
    for (int i = t; i < m; i += 512) {
        unsigned int p = bp[rb + i];
        int dl = p >> 17;
        int r = atomicAdd(&dcount[dl], 1);
        csr[rb + doff[dl] + r] = (int)(p & 0x1FFFFu);
    }
}

// ---------------- K5: fused layer-1 aggregate + ReLU + layer-2 node ----------
// 16 threads per dst: t = (half<<3)|h, 2-edge unroll per lane. (R11 version)
__global__ __launch_bounds__(256) void k_agg1(
    const __half* __restrict__ h1, const float* __restrict__ s_src,
    const float* __restrict__ s_dst, const float* __restrict__ b1,
    const float* __restrict__ W2, const float* __restrict__ a_src2,
    const float* __restrict__ a_dst2,
    const int* __restrict__ offs, const int* __restrict__ ends,
    const int* __restrict__ csr_src,
    float4* __restrict__ h2packed, float* __restrict__ s2d, int N)
{
    int gid = blockIdx.x * 256 + threadIdx.x;
    if (gid >= N * 16) return;
    int n = gid >> 4;
    int t = gid & 15;
    int h = t & 7;
    int half = t >> 3;
    int beg = offs[n], end = ends[n];
    float sd = s_dst[n * 8 + h];

    float z = 0.f;
    float acc[16];
#pragma unroll
    for (int c = 0; c < 16; ++c) acc[c] = 0.f;

    union U { float4 f; __half2 hh[4]; };
    int i = beg + half;
    for (; i + 2 < end; i += 4) {
        int sA = csr_src[i];
        int sB = csr_src[i + 2];
        const float4* hA = (const float4*)(h1 + (size_t)sA * 128 + h * 16);
        const float4* hB = (const float4*)(h1 + (size_t)sB * 128 + h * 16);
        U a0, a1, b0, b1v;
        a0.f = hA[0]; a1.f = hA[1];
        b0.f = hB[0]; b1v.f = hB[1];
        float eA = s_src[sA * 8 + h] + sd;
        float eB = s_src[sB * 8 + h] + sd;
        eA = (eA > 0.f) ? eA : NEG_SLOPE * eA;
        eB = (eB > 0.f) ? eB : NEG_SLOPE * eB;
        float pA = __expf(eA);
        float pB = __expf(eB);
        z += pA + pB;
#pragma unroll
        for (int k = 0; k < 4; ++k) {
            float2 vA = __half22float2(a0.hh[k]);
            float2 vB = __half22float2(b0.hh[k]);
            acc[2 * k]     += pA * vA.x + pB * vB.x;
            acc[2 * k + 1] += pA * vA.y + pB * vB.y;
        }
#pragma unroll
        for (int k = 0; k < 4; ++k) {
            float2 vA = __half22float2(a1.hh[k]);
            float2 vB = __half22float2(b1v.hh[k]);
            acc[8 + 2 * k] += pA * vA.x + pB * vB.x;
            acc[9 + 2 * k] += pA * vA.y + pB * vB.y;
        }
    }
    if (i < end) {
        int sA = csr_src[i];
        const float4* hA = (const float4*)(h1 + (size_t)sA * 128 + h * 16);
        U a0, a1;
        a0.f = hA[0]; a1.f = hA[1];
        float eA = s_src[sA * 8 + h] + sd;
        eA = (eA > 0.f) ? eA : NEG_SLOPE * eA;
        float pA = __expf(eA);
        z += pA;
#pragma unroll
        for (int k = 0; k < 4; ++k) {
            float2 vA = __half22float2(a0.hh[k]);
            acc[2 * k]     += pA * vA.x;
            acc[2 * k + 1] += pA * vA.y;
        }
#pragma unroll
        for (int k = 0; k < 4; ++k) {
            float2 vA = __half22float2(a1.hh[k]);
            acc[8 + 2 * k] += pA * vA.x;
            acc[9 + 2 * k] += pA * vA.y;
        }
    }

    z += __shfl_xor(z, 8);
#pragma unroll
    for (int c = 0; c < 16; ++c) acc[c] += __shfl_xor(acc[c], 8);

    float inv = 1.f / (z + GAT_EPS);

    float r0 = 0.f, r1 = 0.f, r2 = 0.f;
    const float* bb = b1 + h * 16;
    const float* w2 = W2 + h * 16 * 3;
#pragma unroll
    for (int c = 0; c < 16; ++c) {
        float xc = fmaxf(acc[c] * inv + bb[c], 0.f);
        r0 += xc * w2[c * 3 + 0];
        r1 += xc * w2[c * 3 + 1];
        r2 += xc * w2[c * 3 + 2];
    }
#pragma unroll
    for (int m = 4; m >= 1; m >>= 1) {
        r0 += __shfl_xor(r0, m);
        r1 += __shfl_xor(r1, m);
        r2 += __shfl_xor(r2, m);
    }
    if (t == 0) {
        float ss = r0 * a_src2[0] + r1 * a_src2[1] + r2 * a_src2[2];
        float dd = r0 * a_dst2[0] + r1 * a_dst2[1] + r2 * a_dst2[2];
        float4 pk = { r0, r1, r2, ss };
        h2packed[n] = pk;
        s2d[n] = dd;
    }
}

// ---------------- K6: layer-2 aggregate -> out. 8 threads per dst ------------
__global__ __launch_bounds__(256) void k_agg2(
    const float4* __restrict__ h2packed, const float* __restrict__ s2d,
    const float* __restrict__ b2,
    const int* __restrict__ offs, const int* __restrict__ ends,
    const int* __restrict__ csr_src,
    float* __restrict__ out, int N)
{
    int gid = blockIdx.x * 256 + threadIdx.x;
    if (gid >= N * 8) return;
    int n = gid >> 3;
    int t = gid & 7;
    int beg = offs[n], end = ends[n];
    float sd = s2d[n];
    float z = 0.f, a0 = 0.f, a1 = 0.f, a2 = 0.f;
    for (int i = beg + t; i < end; i += 8) {
        int src = csr_src[i];
        float4 v = h2packed[src];
        float s = v.w + sd;
        s = (s > 0.f) ? s : NEG_SLOPE * s;
        float p = __expf(s);
        z += p;
        a0 += p * v.x; a1 += p * v.y; a2 += p * v.z;
    }
#pragma unroll
    for (int m = 4; m >= 1; m >>= 1) {
        z  += __shfl_xor(z, m);
        a0 += __shfl_xor(a0, m);
        a1 += __shfl_xor(a1, m);
        a2 += __shfl_xor(a2, m);
    }
    if (t == 0) {
        float inv = 1.f / (z + GAT_EPS);
        out[(size_t)n * 3 + 0] = a0 * inv + b2[0];
        out[(size_t)n * 3 + 1] = a1 * inv + b2[1];
        out[(size_t)n * 3 + 2] = a2 * inv + b2[2];
    }
}

extern "C" void kernel_launch(void* const* d_in, const int* in_sizes, int n_in,
                              void* d_out, int out_size, void* d_ws, size_t ws_size,
                              hipStream_t stream)
{
    const float* feature = (const float*)d_in[0];
    const int*   ei      = (const int*)d_in[1];
    // d_in[2] edge_type: unused by reference
    const float* W1      = (const float*)d_in[3];
    const float* a_src1  = (const float*)d_in[4];
    const float* a_dst1  = (const float*)d_in[5];
    const float* b1      = (const float*)d_in[6];
    const float* W2      = (const float*)d_in[7];
    const float* a_src2  = (const float*)d_in[8];
    const float* a_dst2  = (const float*)d_in[9];
    const float* b2      = (const float*)d_in[10];

    const int N = in_sizes[0] / 16;
    const int E = in_sizes[1] / 2;
    const int ET = E + N;
    const int NB = (N + 255) >> 8;          // 391 for N=100000 (<= NBMAX)

    char* p = (char*)d_ws;
    auto alloc = [&](size_t bytes) -> void* {
        void* r = (void*)p;
        p += (bytes + 255) & ~(size_t)255;
        return r;
    };
    __half* h1   = (__half*)alloc((size_t)N * 128 * 2);
    float*  s1s  = (float*)alloc((size_t)N * 8 * 4);
    float*  s1d  = (float*)alloc((size_t)N * 8 * 4);
    float4* h2pk = (float4*)alloc((size_t)N * 16);
    float*  s2dv = (float*)alloc((size_t)N * 4);
    int*    offs = (int*)alloc((size_t)N * 4);
    int*    ends = (int*)alloc((size_t)N * 4);
    int*    csr  = (int*)alloc((size_t)NB * CAP * 4);
    unsigned int* bp = (unsigned int*)alloc((size_t)NB * CAP * 4);
    int*    cnt  = (int*)alloc((size_t)NBMAX * 4);

    hipMemsetAsync(cnt, 0, (size_t)NB * 4, stream);

    // edge partition
    int G2 = (ET + 4095) / 4096;
    k_part<<<G2, 1024, 0, stream>>>(ei, E, N, NB, cnt, bp);

    // layer-1 node transform + scores
    k_gemm1<<<(N * 32 + 255) / 256, 256, 0, stream>>>(
        feature, W1, a_src1, a_dst1, h1, s1s, s1d, N);

    // per-bucket CSR build
    k_csr<<<NB, 512, 0, stream>>>(bp, cnt, offs, ends, csr, N);

    // fused layer-1 aggregation + layer-2 node transform (16 thr/dst)
    k_agg1<<<(N * 16 + 255) / 256, 256, 0, stream>>>(
        h1, s1s, s1d, b1, W2, a_src2, a_dst2, offs, ends, csr, h2pk, s2dv, N);

    // layer-2 aggregation -> out
    k_agg2<<<(N * 8 + 255) / 256, 256, 0, stream>>>(
        h2pk, s2dv, b2, offs, ends, csr, (float*)d_out, N);
}